// Round 2
// baseline (210.052 us; speedup 1.0000x reference)
//
#include <hip/hip_runtime.h>
#include <hip/hip_bf16.h>

typedef short bf16x8 __attribute__((ext_vector_type(8)));
typedef float floatx4 __attribute__((ext_vector_type(4)));

#define HW 3136
#define NROW 96

// ---- bf16 bit helpers (RNE) ----
__device__ __forceinline__ unsigned short f2bf(float f) {
    unsigned int u = __float_as_uint(f);
    unsigned int r = (u + 0x7FFFu + ((u >> 16) & 1u)) >> 16;
    return (unsigned short)r;
}
__device__ __forceinline__ float bf2f(unsigned short u) {
    return __uint_as_float(((unsigned int)u) << 16);
}

// ---- y (workspace) load/store, templated on storage type ----
__device__ __forceinline__ void sty(float* p, float v) { *p = v; }
__device__ __forceinline__ void sty(unsigned short* p, float v) { *p = f2bf(v); }
__device__ __forceinline__ float ldy(const float* p) { return *p; }
__device__ __forceinline__ float ldy(const unsigned short* p) { return bf2f(*p); }

// ---- generic param load: bf16 or fp32 buffer ----
__device__ __forceinline__ float ldp(const void* p, int i, int isb) {
    return isb ? bf2f(((const unsigned short*)p)[i]) : ((const float*)p)[i];
}

// ---- on-device dtype detection ----
// bn1_var values are in [1.0, 1.5]. In bf16, every even-indexed ushort is a
// bf16 value in [0x3F80, 0x3FC0]. In fp32, even ushorts are random low
// mantissa bits: P(all 64 in window) ~ (1e-3)^64 ~ 0. Wave-uniform result.
__device__ __forceinline__ int detect_bf16(const void* varp, int* sflag) {
    if (threadIdx.x == 0) {
        const unsigned short* p = (const unsigned short*)varp;
        int ok = 1;
        for (int i = 0; i < 64; ++i) {
            unsigned short v = p[2 * i];
            if (v < 0x3F80u || v > 0x3FC0u) { ok = 0; break; }
        }
        *sflag = ok;
    }
    __syncthreads();
    return *sflag;
}

// ---------------------------------------------------------------------------
// Kernel A: y[n][r][l] = sum_c Wcat[r][c] * x[n][c][l]   (r in [0,96))
// rows 0-15 = conv1_w, 16-31 = conv2_w, 32-95 = conv3_w.
// MFMA 16x16x32 bf16; W staged in LDS with row stride 264 (+8 pad).
// ---------------------------------------------------------------------------
template <typename YT>
__global__ __launch_bounds__(256) void proj_kernel(
    const void* __restrict__ x,
    const void* __restrict__ w1,
    const void* __restrict__ w2,
    const void* __restrict__ w3,
    const void* __restrict__ bn1v,
    YT* __restrict__ y)
{
    __shared__ unsigned short wlds[NROW * 264];
    __shared__ int sflag;
    const int isb = detect_bf16(bn1v, &sflag);

    const int tid = threadIdx.x;
    for (int idx = tid; idx < NROW * 256; idx += 256) {
        const int row = idx >> 8, c = idx & 255;
        const int srow = (row < 16) ? row : ((row < 32) ? row - 16 : row - 32);
        const void* wsrc = (row < 16) ? w1 : ((row < 32) ? w2 : w3);
        unsigned short bits;
        if (isb) bits = ((const unsigned short*)wsrc)[srow * 256 + c];
        else     bits = f2bf(((const float*)wsrc)[srow * 256 + c]);
        wlds[row * 264 + c] = bits;
    }
    __syncthreads();

    const int blk  = blockIdx.x;
    const int n    = blk / 49, tile = blk % 49;   // 49 * 64 = 3136 pixels
    const int wave = tid >> 6, lane = tid & 63;
    const int col  = lane & 15, quad = lane >> 4;
    const int l0   = tile * 64 + wave * 16;
    const size_t xoff = (size_t)n * 256 * HW + l0 + col;
    const unsigned short* xb16 = (const unsigned short*)x + xoff;
    const float*          xbf  = (const float*)x + xoff;

    floatx4 acc[6];
    const floatx4 zero4 = {0.f, 0.f, 0.f, 0.f};
    #pragma unroll
    for (int r = 0; r < 6; ++r) acc[r] = zero4;

    #pragma unroll
    for (int q = 0; q < 8; ++q) {
        const int cbase = q * 32 + quad * 8;
        bf16x8 bfrag;                              // B[k][pix]: k = quad*8+j
        if (isb) {
            #pragma unroll
            for (int j = 0; j < 8; ++j)
                bfrag[j] = (short)xb16[(size_t)(cbase + j) * HW];
        } else {
            #pragma unroll
            for (int j = 0; j < 8; ++j)
                bfrag[j] = (short)f2bf(xbf[(size_t)(cbase + j) * HW]);
        }
        #pragma unroll
        for (int r = 0; r < 6; ++r) {
            bf16x8 afrag = *((const bf16x8*)&wlds[(r * 16 + col) * 264 + cbase]);
            acc[r] = __builtin_amdgcn_mfma_f32_16x16x32_bf16(afrag, bfrag, acc[r], 0, 0, 0);
        }
    }

    // C/D layout: col = lane&15 (pixel), row = quad*4 + reg (out channel)
    YT* yb = y + (size_t)n * NROW * HW + l0 + col;
    #pragma unroll
    for (int r = 0; r < 6; ++r) {
        #pragma unroll
        for (int g = 0; g < 4; ++g)
            sty(yb + (size_t)(r * 16 + quad * 4 + g) * HW, acc[r][g]);
    }
}

// ---------------------------------------------------------------------------
// Kernel B: per-pixel fused attention.
// ---------------------------------------------------------------------------
template <int J0, int JN, typename YT>
__device__ __forceinline__ void jgroup(
    const YT* __restrict__ ybase, int l, const int (&nbr)[9],
    const float (&dlw)[9], const float (&dlh)[9],
    float a1, float c1, float a2, float c2,
    const float* __restrict__ w1f, const float* __restrict__ w2f,
    const float* __restrict__ cpf, float (&h2)[8][9])
{
    float h1[16][JN];
    #pragma unroll
    for (int o = 0; o < 16; ++o)
        #pragma unroll
        for (int j = 0; j < JN; ++j) h1[o][j] = 0.f;

    #pragma unroll
    for (int c = 0; c < 16; ++c) {
        float y1v = ldy(ybase + (size_t)c * HW + l);
        const YT* y2r = ybase + (size_t)(16 + c) * HW;
        float rj[JN];
        #pragma unroll
        for (int j = 0; j < JN; ++j)
            rj[j] = fmaxf(fmaf(y1v - ldy(y2r + nbr[J0 + j]), a1, c1), 0.f);
        #pragma unroll
        for (int o = 0; o < 16; ++o) {
            float wv = w1f[o * 18 + c];
            #pragma unroll
            for (int j = 0; j < JN; ++j) h1[o][j] = fmaf(wv, rj[j], h1[o][j]);
        }
    }
    // position channels 16,17
    #pragma unroll
    for (int j = 0; j < JN; ++j) {
        float p0 = fmaxf(fmaf(cpf[0] * dlw[J0 + j] + cpf[1] * dlh[J0 + j], a1, c1), 0.f);
        float p1 = fmaxf(fmaf(cpf[2] * dlw[J0 + j] + cpf[3] * dlh[J0 + j], a1, c1), 0.f);
        #pragma unroll
        for (int o = 0; o < 16; ++o) {
            h1[o][j] = fmaf(w1f[o * 18 + 16], p0, h1[o][j]);
            h1[o][j] = fmaf(w1f[o * 18 + 17], p1, h1[o][j]);
        }
    }
    // BN2 + ReLU, then convw2 into h2
    #pragma unroll
    for (int c = 0; c < 16; ++c) {
        #pragma unroll
        for (int j = 0; j < JN; ++j) h1[c][j] = fmaxf(fmaf(h1[c][j], a2, c2), 0.f);
        #pragma unroll
        for (int o = 0; o < 8; ++o) {
            float wv = w2f[o * 16 + c];
            #pragma unroll
            for (int j = 0; j < JN; ++j) h2[o][J0 + j] = fmaf(wv, h1[c][j], h2[o][J0 + j]);
        }
    }
}

template <typename YT>
__global__ __launch_bounds__(64) void attn_kernel(
    const YT* __restrict__ y,
    const void* __restrict__ cpw,
    const void* __restrict__ cw1,
    const void* __restrict__ cw2,
    const void* __restrict__ b1g, const void* __restrict__ b1b,
    const void* __restrict__ b1m, const void* __restrict__ b1v,
    const void* __restrict__ b2g, const void* __restrict__ b2b,
    const void* __restrict__ b2m, const void* __restrict__ b2v,
    void* __restrict__ out)
{
    __shared__ float w1f[288];
    __shared__ float w2f[128];
    __shared__ float cpf[4];
    __shared__ int sflag;
    const int isb = detect_bf16(b1v, &sflag);

    const int tid = threadIdx.x;
    for (int i = tid; i < 288; i += 64) w1f[i] = ldp(cw1, i, isb);
    for (int i = tid; i < 128; i += 64) w2f[i] = ldp(cw2, i, isb);
    if (tid < 4) cpf[tid] = ldp(cpw, tid, isb);
    __syncthreads();

    const int blk = blockIdx.x;
    const int n = blk / 49;
    const int l = (blk % 49) * 64 + tid;
    const int h = l / 56, w = l - h * 56;

    // BN params are per-PIXEL scalars (BN over the HW axis)
    const float a1 = ldp(b1g, l, isb) * rsqrtf(ldp(b1v, l, isb) + 1e-3f);
    const float c1 = ldp(b1b, l, isb) - ldp(b1m, l, isb) * a1;
    const float a2 = ldp(b2g, l, isb) * rsqrtf(ldp(b2v, l, isb) + 1e-3f);
    const float c2 = ldp(b2b, l, isb) - ldp(b2m, l, isb) * a2;

    int nbr[9]; float dlw[9], dlh[9];
    #pragma unroll
    for (int dy = 0; dy < 3; ++dy) {
        #pragma unroll
        for (int dx = 0; dx < 3; ++dx) {
            int hh = h + dy - 1; hh = (hh < 0) ? -hh : ((hh > 55) ? 110 - hh : hh);
            int ww = w + dx - 1; ww = (ww < 0) ? -ww : ((ww > 55) ? 110 - ww : ww);
            const int j = dy * 3 + dx;
            nbr[j] = hh * 56 + ww;
            dlw[j] = (float)(w - ww) * (2.0f / 55.0f);  // loc_w(center)-loc_w(nbr)
            dlh[j] = (float)(h - hh) * (2.0f / 55.0f);
        }
    }

    const YT* ybase = y + (size_t)n * NROW * HW;

    float h2[8][9];
    #pragma unroll
    for (int o = 0; o < 8; ++o)
        #pragma unroll
        for (int j = 0; j < 9; ++j) h2[o][j] = 0.f;

    jgroup<0, 5>(ybase, l, nbr, dlw, dlh, a1, c1, a2, c2, w1f, w2f, cpf, h2);
    jgroup<5, 4>(ybase, l, nbr, dlw, dlh, a1, c1, a2, c2, w1f, w2f, cpf, h2);

    // softmax over the 9 window positions, in place
    #pragma unroll
    for (int o = 0; o < 8; ++o) {
        float m = h2[o][0];
        #pragma unroll
        for (int j = 1; j < 9; ++j) m = fmaxf(m, h2[o][j]);
        float s = 0.f;
        #pragma unroll
        for (int j = 0; j < 9; ++j) { float e = __expf(h2[o][j] - m); h2[o][j] = e; s += e; }
        float inv = 1.f / s;
        #pragma unroll
        for (int j = 0; j < 9; ++j) h2[o][j] *= inv;
    }

    // aggregation: out[n][ch][l] = sum_j w[ch&7][j] * y3[ch][nbr_j]
    const size_t obase = (size_t)n * 64 * HW + l;
    #pragma unroll
    for (int cg = 0; cg < 4; ++cg) {
        float acc[16];
        #pragma unroll
        for (int cc = 0; cc < 16; ++cc) acc[cc] = 0.f;
        #pragma unroll
        for (int j = 0; j < 9; ++j) {
            const YT* y3 = ybase + (size_t)(32 + cg * 16) * HW + nbr[j];
            #pragma unroll
            for (int cc = 0; cc < 16; ++cc)
                acc[cc] = fmaf(h2[cc & 7][j], ldy(y3 + (size_t)cc * HW), acc[cc]);
        }
        #pragma unroll
        for (int cc = 0; cc < 16; ++cc) {
            const size_t oi = obase + (size_t)(cg * 16 + cc) * HW;
            if (isb) ((unsigned short*)out)[oi] = f2bf(acc[cc]);
            else     ((float*)out)[oi]          = acc[cc];
        }
    }
}

extern "C" void kernel_launch(void* const* d_in, const int* in_sizes, int n_in,
                              void* d_out, int out_size, void* d_ws, size_t ws_size,
                              hipStream_t stream)
{
    const size_t need_f32 = (size_t)16 * NROW * HW * 4;  // 19,267,584 B
    const bool y32 = ws_size >= need_f32;                // static per capture

    if (y32) {
        float* y = (float*)d_ws;
        proj_kernel<float><<<dim3(784), dim3(256), 0, stream>>>(
            d_in[0], d_in[1], d_in[2], d_in[3], d_in[10], y);
        attn_kernel<float><<<dim3(784), dim3(64), 0, stream>>>(
            y, d_in[4], d_in[5], d_in[6],
            d_in[7], d_in[8], d_in[9], d_in[10],
            d_in[11], d_in[12], d_in[13], d_in[14], d_out);
    } else {
        unsigned short* y = (unsigned short*)d_ws;
        proj_kernel<unsigned short><<<dim3(784), dim3(256), 0, stream>>>(
            d_in[0], d_in[1], d_in[2], d_in[3], d_in[10], y);
        attn_kernel<unsigned short><<<dim3(784), dim3(64), 0, stream>>>(
            y, d_in[4], d_in[5], d_in[6],
            d_in[7], d_in[8], d_in[9], d_in[10],
            d_in[11], d_in[12], d_in[13], d_in[14], d_out);
    }
}

// Round 3
// 170.623 us; speedup vs baseline: 1.2311x; 1.2311x over previous
//
#include <hip/hip_runtime.h>
#include <hip/hip_bf16.h>

typedef short bf16x8 __attribute__((ext_vector_type(8)));
typedef float floatx4 __attribute__((ext_vector_type(4)));
typedef unsigned short ushort4v __attribute__((ext_vector_type(4)));

#define HW 3136
#define NPIX 50176   // 16 * 3136

// ---- bf16 bit helpers (RNE) ----
__device__ __forceinline__ unsigned short f2bf(float f) {
    unsigned int u = __float_as_uint(f);
    unsigned int r = (u + 0x7FFFu + ((u >> 16) & 1u)) >> 16;
    return (unsigned short)r;
}
__device__ __forceinline__ float bf2f(unsigned short u) {
    return __uint_as_float(((unsigned int)u) << 16);
}

__device__ __forceinline__ void sty(float* p, float v) { *p = v; }
__device__ __forceinline__ void sty(unsigned short* p, float v) { *p = f2bf(v); }
__device__ __forceinline__ float ldy(const float* p) { return *p; }
__device__ __forceinline__ float ldy(const unsigned short* p) { return bf2f(*p); }

__device__ __forceinline__ float ldp(const void* p, int i, int isb) {
    return isb ? bf2f(((const unsigned short*)p)[i]) : ((const float*)p)[i];
}

// ---- on-device dtype detection (bn1_var in [1.0,1.5]) ----
__device__ __forceinline__ int detect_bf16(const void* varp, int* sflag) {
    if (threadIdx.x == 0) {
        const unsigned short* p = (const unsigned short*)varp;
        int ok = 1;
        for (int i = 0; i < 64; ++i) {
            unsigned short v = p[2 * i];
            if (v < 0x3F80u || v > 0x3FC0u) { ok = 0; break; }
        }
        *sflag = ok;
    }
    __syncthreads();
    return *sflag;
}

// ---------------------------------------------------------------------------
// Kernel A: y[n][r][l] = sum_c Wcat[r][c] * x[n][c][l], y stored bf16.
// 4 MFMA pixel-tiles per wave: lane col c owns pixels 4c..4c+3, so one
// dwordx2 (ushort4) load feeds all 4 tiles at one channel. Wave pair splits
// the 96 rows (3 row-groups each). No LDS: A-fragments direct from global
// (L1-resident, ~24 KB per half). Block = 4 waves = 128 pixels x 96 rows.
// ---------------------------------------------------------------------------
__global__ __launch_bounds__(256) void proj_kernel(
    const void* __restrict__ x,
    const void* __restrict__ w1,
    const void* __restrict__ w2,
    const void* __restrict__ w3,
    const void* __restrict__ bn1v,
    unsigned short* __restrict__ y)
{
    __shared__ int sflag;
    const int isb = detect_bf16(bn1v, &sflag);

    const int tid  = threadIdx.x;
    const int b    = blockIdx.x;
    const int n    = b / 25, pb = b % 25;
    const int wave = tid >> 6, lane = tid & 63;
    const int rh   = wave >> 1;                   // 0: rows 0-47, 1: rows 48-95
    const int l0   = pb * 128 + (wave & 1) * 64;
    if (l0 >= HW) return;
    const int col = lane & 15, quad = lane >> 4;

    const void* wp0 = (rh == 0) ? w1 : w3;
    const void* wp1 = (rh == 0) ? w2 : w3;
    const void* wp2 = w3;
    const int   ro0 = (rh == 0) ? 0 : 16;
    const int   ro1 = (rh == 0) ? 0 : 32;
    const int   ro2 = (rh == 0) ? 0 : 48;

    const size_t xoff = (size_t)n * 256 * HW + l0 + 4 * col;

    floatx4 acc[3][4];
    const floatx4 z4 = {0.f, 0.f, 0.f, 0.f};
    #pragma unroll
    for (int r = 0; r < 3; ++r)
        #pragma unroll
        for (int t = 0; t < 4; ++t) acc[r][t] = z4;

    #pragma unroll
    for (int q = 0; q < 8; ++q) {
        const int cbase = q * 32 + quad * 8;
        ushort4v ld[8];
        if (isb) {
            const unsigned short* xb = (const unsigned short*)x + xoff;
            #pragma unroll
            for (int j = 0; j < 8; ++j)
                ld[j] = *(const ushort4v*)(xb + (size_t)(cbase + j) * HW);
        } else {
            const float* xb = (const float*)x + xoff;
            #pragma unroll
            for (int j = 0; j < 8; ++j) {
                floatx4 f = *(const floatx4*)(xb + (size_t)(cbase + j) * HW);
                #pragma unroll
                for (int t = 0; t < 4; ++t) ld[j][t] = f2bf(f[t]);
            }
        }
        bf16x8 bt[4];
        #pragma unroll
        for (int t = 0; t < 4; ++t)
            #pragma unroll
            for (int j = 0; j < 8; ++j) bt[t][j] = (short)ld[j][t];

        const void* wps[3] = {wp0, wp1, wp2};
        const int   ros[3] = {ro0, ro1, ro2};
        #pragma unroll
        for (int r = 0; r < 3; ++r) {
            bf16x8 af;
            if (isb) {
                af = *(const bf16x8*)((const unsigned short*)wps[r] + (ros[r] + col) * 256 + cbase);
            } else {
                const float* fp = (const float*)wps[r] + (ros[r] + col) * 256 + cbase;
                #pragma unroll
                for (int j = 0; j < 8; ++j) af[j] = (short)f2bf(fp[j]);
            }
            #pragma unroll
            for (int t = 0; t < 4; ++t)
                acc[r][t] = __builtin_amdgcn_mfma_f32_16x16x32_bf16(af, bt[t], acc[r][t], 0, 0, 0);
        }
    }

    // C/D: col = lane&15 -> pixel group, row = quad*4+g; tile t -> pixel 4*col+t
    unsigned short* yb = y + (size_t)n * 96 * HW + l0 + 4 * col;
    #pragma unroll
    for (int r = 0; r < 3; ++r)
        #pragma unroll
        for (int g = 0; g < 4; ++g) {
            const int row = (rh * 3 + r) * 16 + quad * 4 + g;
            ushort4v pk;
            #pragma unroll
            for (int t = 0; t < 4; ++t) pk[t] = f2bf(acc[r][t][g]);
            *(ushort4v*)(yb + (size_t)row * HW) = pk;
        }
}

// ---------------------------------------------------------------------------
// Attention front: per-pixel softmax weights. j-groups of 3 cap VGPRs.
// ---------------------------------------------------------------------------
template <int J0, int JN>
__device__ __forceinline__ void jgroup(
    const unsigned short* __restrict__ ybase, const int (&nbr)[9],
    const float (&y1f)[16],
    const float (&dlw)[9], const float (&dlh)[9],
    float a1, float c1, float a2, float c2,
    const float* __restrict__ w1f, const float* __restrict__ w2f,
    const float* __restrict__ cpf, float (&h2)[8][9])
{
    float h1[16][JN];
    #pragma unroll
    for (int o = 0; o < 16; ++o)
        #pragma unroll
        for (int j = 0; j < JN; ++j) h1[o][j] = 0.f;

    #pragma unroll
    for (int c = 0; c < 16; ++c) {
        const unsigned short* y2r = ybase + (size_t)(16 + c) * HW;
        float rj[JN];
        #pragma unroll
        for (int j = 0; j < JN; ++j)
            rj[j] = fmaxf(fmaf(y1f[c] - bf2f(y2r[nbr[J0 + j]]), a1, c1), 0.f);
        #pragma unroll
        for (int o = 0; o < 16; ++o) {
            float wv = w1f[o * 18 + c];
            #pragma unroll
            for (int j = 0; j < JN; ++j) h1[o][j] = fmaf(wv, rj[j], h1[o][j]);
        }
    }
    #pragma unroll
    for (int j = 0; j < JN; ++j) {
        float p0 = fmaxf(fmaf(cpf[0] * dlw[J0 + j] + cpf[1] * dlh[J0 + j], a1, c1), 0.f);
        float p1 = fmaxf(fmaf(cpf[2] * dlw[J0 + j] + cpf[3] * dlh[J0 + j], a1, c1), 0.f);
        #pragma unroll
        for (int o = 0; o < 16; ++o) {
            h1[o][j] = fmaf(w1f[o * 18 + 16], p0, h1[o][j]);
            h1[o][j] = fmaf(w1f[o * 18 + 17], p1, h1[o][j]);
        }
    }
    #pragma unroll
    for (int c = 0; c < 16; ++c) {
        #pragma unroll
        for (int j = 0; j < JN; ++j) h1[c][j] = fmaxf(fmaf(h1[c][j], a2, c2), 0.f);
        #pragma unroll
        for (int o = 0; o < 8; ++o) {
            float wv = w2f[o * 16 + c];
            #pragma unroll
            for (int j = 0; j < JN; ++j) h2[o][J0 + j] = fmaf(wv, h1[c][j], h2[o][J0 + j]);
        }
    }
}

template <typename WT, int DO_AGG>
__global__ __launch_bounds__(256) void attn_front(
    const unsigned short* __restrict__ y,
    const void* __restrict__ cpw,
    const void* __restrict__ cw1,
    const void* __restrict__ cw2,
    const void* __restrict__ b1g, const void* __restrict__ b1b,
    const void* __restrict__ b1m, const void* __restrict__ b1v,
    const void* __restrict__ b2g, const void* __restrict__ b2b,
    const void* __restrict__ b2m, const void* __restrict__ b2v,
    WT* __restrict__ wbuf,
    void* __restrict__ out)
{
    __shared__ float w1f[288];
    __shared__ float w2f[128];
    __shared__ float cpf[4];
    __shared__ int sflag;
    const int isb = detect_bf16(b1v, &sflag);

    const int tid = threadIdx.x;
    for (int i = tid; i < 288; i += blockDim.x) w1f[i] = ldp(cw1, i, isb);
    for (int i = tid; i < 128; i += blockDim.x) w2f[i] = ldp(cw2, i, isb);
    if (tid < 4) cpf[tid] = ldp(cpw, tid, isb);
    __syncthreads();

    const int gid = blockIdx.x * blockDim.x + tid;
    const int n = gid / HW;
    const int l = gid - n * HW;
    const int h = l / 56, w = l - h * 56;

    const float a1 = ldp(b1g, l, isb) * rsqrtf(ldp(b1v, l, isb) + 1e-3f);
    const float c1 = ldp(b1b, l, isb) - ldp(b1m, l, isb) * a1;
    const float a2 = ldp(b2g, l, isb) * rsqrtf(ldp(b2v, l, isb) + 1e-3f);
    const float c2 = ldp(b2b, l, isb) - ldp(b2m, l, isb) * a2;

    int nbr[9]; float dlw[9], dlh[9];
    #pragma unroll
    for (int dy = 0; dy < 3; ++dy)
        #pragma unroll
        for (int dx = 0; dx < 3; ++dx) {
            int hh = h + dy - 1; hh = (hh < 0) ? -hh : ((hh > 55) ? 110 - hh : hh);
            int ww = w + dx - 1; ww = (ww < 0) ? -ww : ((ww > 55) ? 110 - ww : ww);
            const int j = dy * 3 + dx;
            nbr[j] = hh * 56 + ww;
            dlw[j] = (float)(w - ww) * (2.0f / 55.0f);
            dlh[j] = (float)(h - hh) * (2.0f / 55.0f);
        }

    const unsigned short* ybase = y + (size_t)n * 96 * HW;
    float y1f[16];
    #pragma unroll
    for (int c = 0; c < 16; ++c) y1f[c] = bf2f(ybase[(size_t)c * HW + l]);

    float h2[8][9];
    #pragma unroll
    for (int o = 0; o < 8; ++o)
        #pragma unroll
        for (int j = 0; j < 9; ++j) h2[o][j] = 0.f;

    jgroup<0, 3>(ybase, nbr, y1f, dlw, dlh, a1, c1, a2, c2, w1f, w2f, cpf, h2);
    jgroup<3, 3>(ybase, nbr, y1f, dlw, dlh, a1, c1, a2, c2, w1f, w2f, cpf, h2);
    jgroup<6, 3>(ybase, nbr, y1f, dlw, dlh, a1, c1, a2, c2, w1f, w2f, cpf, h2);

    #pragma unroll
    for (int o = 0; o < 8; ++o) {
        float m = h2[o][0];
        #pragma unroll
        for (int j = 1; j < 9; ++j) m = fmaxf(m, h2[o][j]);
        float s = 0.f;
        #pragma unroll
        for (int j = 0; j < 9; ++j) { float e = __expf(h2[o][j] - m); h2[o][j] = e; s += e; }
        float inv = 1.f / s;
        #pragma unroll
        for (int j = 0; j < 9; ++j) h2[o][j] *= inv;
    }

    if (DO_AGG) {
        const size_t obase = (size_t)n * 64 * HW + l;
        #pragma unroll
        for (int cg = 0; cg < 4; ++cg) {
            float acc[16];
            #pragma unroll
            for (int cc = 0; cc < 16; ++cc) acc[cc] = 0.f;
            #pragma unroll
            for (int j = 0; j < 9; ++j) {
                const unsigned short* y3 = ybase + (size_t)(32 + cg * 16) * HW + nbr[j];
                #pragma unroll
                for (int cc = 0; cc < 16; ++cc)
                    acc[cc] = fmaf(h2[cc & 7][j], bf2f(y3[(size_t)cc * HW]), acc[cc]);
            }
            #pragma unroll
            for (int cc = 0; cc < 16; ++cc) {
                const size_t oi = obase + (size_t)(cg * 16 + cc) * HW;
                if (isb) ((unsigned short*)out)[oi] = f2bf(acc[cc]);
                else     ((float*)out)[oi]          = acc[cc];
            }
        }
    } else {
        WT* wp = wbuf + (size_t)(n * HW + l) * 72;   // [c(8)][j(9)] per pixel
        if constexpr (sizeof(WT) == 2) {
            unsigned int* wp32 = (unsigned int*)wp;
            #pragma unroll
            for (int p = 0; p < 36; ++p) {
                const int i0 = 2 * p, i1 = 2 * p + 1;
                unsigned int lo = f2bf(h2[i0 / 9][i0 % 9]);
                unsigned int hi = f2bf(h2[i1 / 9][i1 % 9]);
                wp32[p] = lo | (hi << 16);
            }
        } else {
            #pragma unroll
            for (int c = 0; c < 8; ++c)
                #pragma unroll
                for (int j = 0; j < 9; ++j) sty(wp + c * 9 + j, h2[c][j]);
        }
    }
}

// ---------------------------------------------------------------------------
// Aggregation: lane = (pixel, channel-group of 16). 3136 waves (12/CU).
// ---------------------------------------------------------------------------
template <typename WT>
__global__ __launch_bounds__(256) void agg_kernel(
    const unsigned short* __restrict__ y,
    const WT* __restrict__ wbuf,
    const void* __restrict__ b1v,
    void* __restrict__ out)
{
    __shared__ int sflag;
    const int isb = detect_bf16(b1v, &sflag);

    const int b = blockIdx.x;
    const int n = b / 49;
    const int l = (b % 49) * 64 + (threadIdx.x & 63);
    const int cg = threadIdx.x >> 6;
    const int h = l / 56, w = l - h * 56;

    int nbr[9];
    #pragma unroll
    for (int dy = 0; dy < 3; ++dy)
        #pragma unroll
        for (int dx = 0; dx < 3; ++dx) {
            int hh = h + dy - 1; hh = (hh < 0) ? -hh : ((hh > 55) ? 110 - hh : hh);
            int ww = w + dx - 1; ww = (ww < 0) ? -ww : ((ww > 55) ? 110 - ww : ww);
            nbr[dy * 3 + dx] = hh * 56 + ww;
        }

    float wf[72];
    const WT* wp = wbuf + (size_t)(n * HW + l) * 72;
    if constexpr (sizeof(WT) == 2) {
        const unsigned int* wp32 = (const unsigned int*)wp;
        #pragma unroll
        for (int p = 0; p < 36; ++p) {
            unsigned int u = wp32[p];
            wf[2 * p]     = bf2f((unsigned short)(u & 0xFFFFu));
            wf[2 * p + 1] = bf2f((unsigned short)(u >> 16));
        }
    } else {
        #pragma unroll
        for (int i = 0; i < 72; ++i) wf[i] = (float)wp[i];
    }

    const unsigned short* y3b = y + (size_t)n * 96 * HW + (size_t)(32 + cg * 16) * HW;
    float acc[16];
    #pragma unroll
    for (int cc = 0; cc < 16; ++cc) acc[cc] = 0.f;
    #pragma unroll
    for (int j = 0; j < 9; ++j) {
        const unsigned short* yp = y3b + nbr[j];
        #pragma unroll
        for (int cc = 0; cc < 16; ++cc)
            acc[cc] = fmaf(wf[(cc & 7) * 9 + j], bf2f(yp[(size_t)cc * HW]), acc[cc]);
    }
    const size_t obase = (size_t)n * 64 * HW + (size_t)(cg * 16) * HW + l;
    #pragma unroll
    for (int cc = 0; cc < 16; ++cc) {
        if (isb) ((unsigned short*)out)[obase + (size_t)cc * HW] = f2bf(acc[cc]);
        else     ((float*)out)[obase + (size_t)cc * HW]          = acc[cc];
    }
}

extern "C" void kernel_launch(void* const* d_in, const int* in_sizes, int n_in,
                              void* d_out, int out_size, void* d_ws, size_t ws_size,
                              hipStream_t stream)
{
    const size_t yB     = (size_t)16 * 96 * HW * 2;   //  9,633,792 B (y bf16)
    const size_t wB_f32 = (size_t)NPIX * 72 * 4;      // 14,450,688 B
    const size_t wB_bf  = (size_t)NPIX * 72 * 2;      //  7,225,344 B

    unsigned short* y = (unsigned short*)d_ws;
    proj_kernel<<<dim3(400), dim3(256), 0, stream>>>(
        d_in[0], d_in[1], d_in[2], d_in[3], d_in[10], y);

    char* wsp = (char*)d_ws + yB;
    if (ws_size >= yB + wB_f32) {
        float* wb = (float*)wsp;
        attn_front<float, 0><<<dim3(196), dim3(256), 0, stream>>>(
            y, d_in[4], d_in[5], d_in[6],
            d_in[7], d_in[8], d_in[9], d_in[10],
            d_in[11], d_in[12], d_in[13], d_in[14], wb, d_out);
        agg_kernel<float><<<dim3(784), dim3(256), 0, stream>>>(y, wb, d_in[10], d_out);
    } else if (ws_size >= yB + wB_bf) {
        unsigned short* wb = (unsigned short*)wsp;
        attn_front<unsigned short, 0><<<dim3(196), dim3(256), 0, stream>>>(
            y, d_in[4], d_in[5], d_in[6],
            d_in[7], d_in[8], d_in[9], d_in[10],
            d_in[11], d_in[12], d_in[13], d_in[14], wb, d_out);
        agg_kernel<unsigned short><<<dim3(784), dim3(256), 0, stream>>>(y, wb, d_in[10], d_out);
    } else {
        // fused fallback (needs only y): aggregation inline
        attn_front<unsigned short, 1><<<dim3(784), dim3(64), 0, stream>>>(
            y, d_in[4], d_in[5], d_in[6],
            d_in[7], d_in[8], d_in[9], d_in[10],
            d_in[11], d_in[12], d_in[13], d_in[14], (unsigned short*)d_ws, d_out);
    }
}

// Round 4
// 166.767 us; speedup vs baseline: 1.2596x; 1.0231x over previous
//
#include <hip/hip_runtime.h>
#include <hip/hip_bf16.h>

typedef short bf16x8 __attribute__((ext_vector_type(8)));
typedef float floatx4 __attribute__((ext_vector_type(4)));
typedef unsigned short ushort4v __attribute__((ext_vector_type(4)));

#define HW 3136
#define NB 16
#define NPIX 50176   // NB * HW

// prep layout (floats)
#define P_CP   0
#define P_W1   4      // 288
#define P_W2   292    // 128
#define P_FLAG 420
#define P_BN   424    // a1[HW], c1[HW], a2[HW], c2[HW]
#define PREP_FLOATS (424 + 4 * HW)

// ---- bf16 bit helpers (RNE) ----
__device__ __forceinline__ unsigned short f2bf(float f) {
    unsigned int u = __float_as_uint(f);
    unsigned int r = (u + 0x7FFFu + ((u >> 16) & 1u)) >> 16;
    return (unsigned short)r;
}
__device__ __forceinline__ float bf2f(unsigned short u) {
    return __uint_as_float(((unsigned int)u) << 16);
}
__device__ __forceinline__ void unp8(uint4 u, float* o) {
    o[0] = bf2f((unsigned short)(u.x & 0xFFFFu)); o[1] = bf2f((unsigned short)(u.x >> 16));
    o[2] = bf2f((unsigned short)(u.y & 0xFFFFu)); o[3] = bf2f((unsigned short)(u.y >> 16));
    o[4] = bf2f((unsigned short)(u.z & 0xFFFFu)); o[5] = bf2f((unsigned short)(u.z >> 16));
    o[6] = bf2f((unsigned short)(u.w & 0xFFFFu)); o[7] = bf2f((unsigned short)(u.w >> 16));
}
__device__ __forceinline__ float ldp(const void* p, int i, int isb) {
    return isb ? bf2f(((const unsigned short*)p)[i]) : ((const float*)p)[i];
}

// ---- on-device dtype detection (bn1_var in [1.0,1.5]) ----
__device__ __forceinline__ int detect_bf16(const void* varp, int* sflag) {
    if (threadIdx.x == 0) {
        const unsigned short* p = (const unsigned short*)varp;
        int ok = 1;
        for (int i = 0; i < 64; ++i) {
            unsigned short v = p[2 * i];
            if (v < 0x3F80u || v > 0x3FC0u) { ok = 0; break; }
        }
        *sflag = ok;
    }
    __syncthreads();
    return *sflag;
}

// ---------------------------------------------------------------------------
// Kernel A: yT[n][l][r] = sum_c Wcat[r][c] * x[n][c][l]  (pixel-major, bf16).
// 4 MFMA pixel-tiles per wave (lane col owns pixels 4c..4c+3; one dwordx2
// feeds 4 tiles). Wave pair splits 96 rows. Block 0 additionally builds the
// fp32 prep array (weights + fused BN coefficients + dtype flag).
// ---------------------------------------------------------------------------
__global__ __launch_bounds__(256) void proj_kernel(
    const void* __restrict__ x,
    const void* __restrict__ w1, const void* __restrict__ w2,
    const void* __restrict__ w3,
    const void* __restrict__ cpw, const void* __restrict__ cw1,
    const void* __restrict__ cw2,
    const void* __restrict__ b1g, const void* __restrict__ b1b,
    const void* __restrict__ b1m, const void* __restrict__ b1v,
    const void* __restrict__ b2g, const void* __restrict__ b2b,
    const void* __restrict__ b2m, const void* __restrict__ b2v,
    unsigned short* __restrict__ y,
    float* __restrict__ prep)
{
    __shared__ int sflag;
    const int isb = detect_bf16(b1v, &sflag);
    const int tid = threadIdx.x;

    if (blockIdx.x == 0) {
        for (int i = tid; i < 4;   i += 256) prep[P_CP + i] = ldp(cpw, i, isb);
        for (int i = tid; i < 288; i += 256) prep[P_W1 + i] = ldp(cw1, i, isb);
        for (int i = tid; i < 128; i += 256) prep[P_W2 + i] = ldp(cw2, i, isb);
        if (tid == 0) prep[P_FLAG] = isb ? 1.f : 0.f;
        for (int i = tid; i < HW; i += 256) {
            float a1 = ldp(b1g, i, isb) * rsqrtf(ldp(b1v, i, isb) + 1e-3f);
            float c1 = ldp(b1b, i, isb) - ldp(b1m, i, isb) * a1;
            float a2 = ldp(b2g, i, isb) * rsqrtf(ldp(b2v, i, isb) + 1e-3f);
            float c2 = ldp(b2b, i, isb) - ldp(b2m, i, isb) * a2;
            prep[P_BN + i]          = a1;
            prep[P_BN + HW + i]     = c1;
            prep[P_BN + 2 * HW + i] = a2;
            prep[P_BN + 3 * HW + i] = c2;
        }
    }

    const int b    = blockIdx.x;
    const int n    = b / 25, pb = b % 25;
    const int wave = tid >> 6, lane = tid & 63;
    const int rh   = wave >> 1;                   // 0: rows 0-47, 1: rows 48-95
    const int l0   = pb * 128 + (wave & 1) * 64;
    if (l0 >= HW) return;
    const int col = lane & 15, quad = lane >> 4;

    const void* wps[3];
    int ros[3];
    if (rh == 0) { wps[0] = w1; wps[1] = w2; wps[2] = w3; ros[0] = 0; ros[1] = 0; ros[2] = 0; }
    else         { wps[0] = w3; wps[1] = w3; wps[2] = w3; ros[0] = 16; ros[1] = 32; ros[2] = 48; }

    const size_t xoff = (size_t)n * 256 * HW + l0 + 4 * col;

    floatx4 acc[3][4];
    const floatx4 z4 = {0.f, 0.f, 0.f, 0.f};
    #pragma unroll
    for (int r = 0; r < 3; ++r)
        #pragma unroll
        for (int t = 0; t < 4; ++t) acc[r][t] = z4;

    #pragma unroll
    for (int q = 0; q < 8; ++q) {
        const int cbase = q * 32 + quad * 8;
        ushort4v ld[8];
        if (isb) {
            const unsigned short* xb = (const unsigned short*)x + xoff;
            #pragma unroll
            for (int j = 0; j < 8; ++j)
                ld[j] = *(const ushort4v*)(xb + (size_t)(cbase + j) * HW);
        } else {
            const float* xb = (const float*)x + xoff;
            #pragma unroll
            for (int j = 0; j < 8; ++j) {
                floatx4 f = *(const floatx4*)(xb + (size_t)(cbase + j) * HW);
                #pragma unroll
                for (int t = 0; t < 4; ++t) ld[j][t] = f2bf(f[t]);
            }
        }
        bf16x8 bt[4];
        #pragma unroll
        for (int t = 0; t < 4; ++t)
            #pragma unroll
            for (int j = 0; j < 8; ++j) bt[t][j] = (short)ld[j][t];

        #pragma unroll
        for (int r = 0; r < 3; ++r) {
            bf16x8 af;
            if (isb) {
                af = *(const bf16x8*)((const unsigned short*)wps[r] + (ros[r] + col) * 256 + cbase);
            } else {
                const float* fp = (const float*)wps[r] + (ros[r] + col) * 256 + cbase;
                #pragma unroll
                for (int j = 0; j < 8; ++j) af[j] = (short)f2bf(fp[j]);
            }
            #pragma unroll
            for (int t = 0; t < 4; ++t)
                acc[r][t] = __builtin_amdgcn_mfma_f32_16x16x32_bf16(af, bt[t], acc[r][t], 0, 0, 0);
        }
    }

    // C/D: col -> pixel group, row = quad*4+g. Transposed store: yT[pixel][ch].
    unsigned short* yb = y + ((size_t)n * HW + l0 + 4 * col) * 96 + rh * 48 + quad * 4;
    #pragma unroll
    for (int r = 0; r < 3; ++r)
        #pragma unroll
        for (int t = 0; t < 4; ++t) {
            ushort4v pk;
            #pragma unroll
            for (int g = 0; g < 4; ++g) pk[g] = f2bf(acc[r][t][g]);
            *(ushort4v*)(yb + (size_t)t * 96 + r * 16) = pk;
        }
}

// ---------------------------------------------------------------------------
// attn_w: thread = (pixel, j). Computes pre-softmax h2[8] -> wbuf[p][j][8].
// Weights/BN coeffs via uniform s_load from prep. Barrier-free, ~75 VGPR.
// ---------------------------------------------------------------------------
template <typename WT>
__global__ __launch_bounds__(256, 4) void attn_w_kernel(
    const unsigned short* __restrict__ yT,
    const float* __restrict__ prep,
    WT* __restrict__ wbuf)
{
    const int tid = threadIdx.x;
    const int bid = blockIdx.x;
    const int pb = bid / 9;
    const int j  = bid - pb * 9;          // uniform per block
    const int p  = pb * 256 + tid;        // < 50176 exactly
    const int n  = p / HW;
    const int l  = p - n * HW;
    const int h  = l / 56, w = l - h * 56;
    const int dy = j / 3 - 1, dx = (j % 3) - 1;
    int hh = h + dy; hh = (hh < 0) ? -hh : ((hh > 55) ? 110 - hh : hh);
    int ww = w + dx; ww = (ww < 0) ? -ww : ((ww > 55) ? 110 - ww : ww);
    const int nbr = hh * 56 + ww;

    const float a1 = prep[P_BN + l];
    const float c1 = prep[P_BN + HW + l];
    const float a2 = prep[P_BN + 2 * HW + l];
    const float c2 = prep[P_BN + 3 * HW + l];

    const unsigned short* y1p = yT + ((size_t)n * HW + l) * 96;
    const unsigned short* y2p = yT + ((size_t)n * HW + nbr) * 96 + 16;
    float y1f[16], y2f[16];
    unp8(*(const uint4*)y1p, y1f);       unp8(*(const uint4*)(y1p + 8), y1f + 8);
    unp8(*(const uint4*)y2p, y2f);       unp8(*(const uint4*)(y2p + 8), y2f + 8);

    float rel[18];
    #pragma unroll
    for (int c = 0; c < 16; ++c)
        rel[c] = fmaxf(fmaf(y1f[c] - y2f[c], a1, c1), 0.f);
    const float dlw = (float)(w - ww) * (2.0f / 55.0f);
    const float dlh = (float)(h - hh) * (2.0f / 55.0f);
    rel[16] = fmaxf(fmaf(prep[P_CP + 0] * dlw + prep[P_CP + 1] * dlh, a1, c1), 0.f);
    rel[17] = fmaxf(fmaf(prep[P_CP + 2] * dlw + prep[P_CP + 3] * dlh, a1, c1), 0.f);

    float h1[16];
    #pragma unroll
    for (int o = 0; o < 16; ++o) {
        float s = 0.f;
        #pragma unroll
        for (int c = 0; c < 18; ++c)
            s = fmaf(prep[P_W1 + o * 18 + c], rel[c], s);
        h1[o] = fmaxf(fmaf(s, a2, c2), 0.f);
    }
    float h2[8];
    #pragma unroll
    for (int o2 = 0; o2 < 8; ++o2) {
        float s = 0.f;
        #pragma unroll
        for (int o = 0; o < 16; ++o)
            s = fmaf(prep[P_W2 + o2 * 16 + o], h1[o], s);
        h2[o2] = s;
    }

    WT* wp = wbuf + ((size_t)p * 9 + j) * 8;
    if constexpr (sizeof(WT) == 4) {
        floatx4 v0 = {h2[0], h2[1], h2[2], h2[3]};
        floatx4 v1 = {h2[4], h2[5], h2[6], h2[7]};
        *(floatx4*)wp       = v0;
        *(floatx4*)(wp + 4) = v1;
    } else {
        uint4 pk;
        pk.x = (unsigned int)f2bf(h2[0]) | ((unsigned int)f2bf(h2[1]) << 16);
        pk.y = (unsigned int)f2bf(h2[2]) | ((unsigned int)f2bf(h2[3]) << 16);
        pk.z = (unsigned int)f2bf(h2[4]) | ((unsigned int)f2bf(h2[5]) << 16);
        pk.w = (unsigned int)f2bf(h2[6]) | ((unsigned int)f2bf(h2[7]) << 16);
        *(uint4*)wp = pk;
    }
}

// ---------------------------------------------------------------------------
// agg: wave = channel-group of 16, lane = pixel. Softmax over j (deferred
// normalization) + weighted neighbor sum with dwordx4 y3 loads.
// ---------------------------------------------------------------------------
template <typename WT>
__global__ __launch_bounds__(256, 3) void agg_kernel(
    const unsigned short* __restrict__ yT,
    const WT* __restrict__ wbuf,
    const float* __restrict__ prep,
    void* __restrict__ out)
{
    const int isb = prep[P_FLAG] != 0.f;
    const int b = blockIdx.x;
    const int n = b / 49;
    const int l = (b - n * 49) * 64 + (threadIdx.x & 63);
    const int cg = threadIdx.x >> 6;
    const int h = l / 56, w = l - h * 56;

    int nbr[9];
    #pragma unroll
    for (int dy = 0; dy < 3; ++dy)
        #pragma unroll
        for (int dx = 0; dx < 3; ++dx) {
            int hh = h + dy - 1; hh = (hh < 0) ? -hh : ((hh > 55) ? 110 - hh : hh);
            int ww = w + dx - 1; ww = (ww < 0) ? -ww : ((ww > 55) ? 110 - ww : ww);
            nbr[dy * 3 + dx] = hh * 56 + ww;
        }

    float wf[72];
    const WT* wp = wbuf + (size_t)(n * HW + l) * 72;
    if constexpr (sizeof(WT) == 4) {
        #pragma unroll
        for (int i = 0; i < 18; ++i)
            *(floatx4*)(wf + 4 * i) = *(const floatx4*)(wp + 4 * i);
    } else {
        #pragma unroll
        for (int i = 0; i < 9; ++i) {
            uint4 u = *(const uint4*)(wp + 8 * i);
            unp8(u, wf + 8 * i);
        }
    }

    float inv[8];
    #pragma unroll
    for (int c = 0; c < 8; ++c) {
        float m = wf[c];
        #pragma unroll
        for (int j = 1; j < 9; ++j) m = fmaxf(m, wf[j * 8 + c]);
        float s = 0.f;
        #pragma unroll
        for (int j = 0; j < 9; ++j) {
            float e = __expf(wf[j * 8 + c] - m);
            wf[j * 8 + c] = e;
            s += e;
        }
        inv[c] = 1.f / s;
    }

    const unsigned short* y3b = yT + (size_t)n * HW * 96 + 32 + cg * 16;
    float acc[16];
    #pragma unroll
    for (int cc = 0; cc < 16; ++cc) acc[cc] = 0.f;
    #pragma unroll
    for (int j = 0; j < 9; ++j) {
        const unsigned short* yp = y3b + (size_t)nbr[j] * 96;
        float yv[16];
        unp8(*(const uint4*)yp, yv);
        unp8(*(const uint4*)(yp + 8), yv + 8);
        #pragma unroll
        for (int cc = 0; cc < 16; ++cc)
            acc[cc] = fmaf(wf[j * 8 + (cc & 7)], yv[cc], acc[cc]);
    }

    const size_t obase = ((size_t)n * 64 + cg * 16) * HW + l;
    #pragma unroll
    for (int cc = 0; cc < 16; ++cc) {
        float v = acc[cc] * inv[cc & 7];
        if (isb) ((unsigned short*)out)[obase + (size_t)cc * HW] = f2bf(v);
        else     ((float*)out)[obase + (size_t)cc * HW]          = v;
    }
}

extern "C" void kernel_launch(void* const* d_in, const int* in_sizes, int n_in,
                              void* d_out, int out_size, void* d_ws, size_t ws_size,
                              hipStream_t stream)
{
    const size_t yB    = (size_t)NB * HW * 96 * 2;   //  9,633,792
    const size_t wB32  = (size_t)NPIX * 72 * 4;      // 14,450,688
    const size_t wB16  = (size_t)NPIX * 72 * 2;      //  7,225,344
    const size_t prepB = (size_t)PREP_FLOATS * 4;    //     52,064

    const bool w32 = ws_size >= yB + wB32 + prepB;   // static per capture
    unsigned short* y = (unsigned short*)d_ws;
    char* wsp = (char*)d_ws + yB;
    float* prep = (float*)((char*)d_ws + yB + (w32 ? wB32 : wB16));

    proj_kernel<<<dim3(400), dim3(256), 0, stream>>>(
        d_in[0], d_in[1], d_in[2], d_in[3],
        d_in[4], d_in[5], d_in[6],
        d_in[7], d_in[8], d_in[9], d_in[10],
        d_in[11], d_in[12], d_in[13], d_in[14],
        y, prep);

    if (w32) {
        float* wb = (float*)wsp;
        attn_w_kernel<float><<<dim3(1764), dim3(256), 0, stream>>>(y, prep, wb);
        agg_kernel<float><<<dim3(784), dim3(256), 0, stream>>>(y, wb, prep, d_out);
    } else {
        unsigned short* wb = (unsigned short*)wsp;
        attn_w_kernel<unsigned short><<<dim3(1764), dim3(256), 0, stream>>>(y, prep, wb);
        agg_kernel<unsigned short><<<dim3(784), dim3(256), 0, stream>>>(y, wb, prep, d_out);
    }
}

// Round 5
// 165.590 us; speedup vs baseline: 1.2685x; 1.0071x over previous
//
#include <hip/hip_runtime.h>

typedef short bf16x8 __attribute__((ext_vector_type(8)));
typedef float floatx4 __attribute__((ext_vector_type(4)));
typedef unsigned short ushort4v __attribute__((ext_vector_type(4)));

#define HW 3136
#define NB 16

// prep layout (floats)
#define P_CP   0
#define P_W1   4      // 288
#define P_W2   292    // 128
#define P_FLAG 420
#define P_BN   424    // a1[HW], c1[HW], a2[HW], c2[HW]
#define PREP_FLOATS (424 + 4 * HW)

// LDS stride (floats) for the fused attn kernel: 100*4=400 B per pixel.
// (100*p)%32 = (4p)%32 -> 8 bank-groups, 8 lanes each, 8 dwords/bank on b128
// = conflict-free-equivalent; 400p is 16-B aligned.
#define WS 100

// ---- bf16 bit helpers (RNE) ----
__device__ __forceinline__ unsigned short f2bf(float f) {
    unsigned int u = __float_as_uint(f);
    unsigned int r = (u + 0x7FFFu + ((u >> 16) & 1u)) >> 16;
    return (unsigned short)r;
}
__device__ __forceinline__ float bf2f(unsigned short u) {
    return __uint_as_float(((unsigned int)u) << 16);
}
__device__ __forceinline__ void unp8(uint4 u, float* o) {
    o[0] = bf2f((unsigned short)(u.x & 0xFFFFu)); o[1] = bf2f((unsigned short)(u.x >> 16));
    o[2] = bf2f((unsigned short)(u.y & 0xFFFFu)); o[3] = bf2f((unsigned short)(u.y >> 16));
    o[4] = bf2f((unsigned short)(u.z & 0xFFFFu)); o[5] = bf2f((unsigned short)(u.z >> 16));
    o[6] = bf2f((unsigned short)(u.w & 0xFFFFu)); o[7] = bf2f((unsigned short)(u.w >> 16));
}
__device__ __forceinline__ float ldp(const void* p, int i, int isb) {
    return isb ? bf2f(((const unsigned short*)p)[i]) : ((const float*)p)[i];
}

// ---- on-device dtype detection (bn1_var in [1.0,1.5]) ----
__device__ __forceinline__ int detect_bf16(const void* varp, int* sflag) {
    if (threadIdx.x == 0) {
        const unsigned short* p = (const unsigned short*)varp;
        int ok = 1;
        for (int i = 0; i < 64; ++i) {
            unsigned short v = p[2 * i];
            if (v < 0x3F80u || v > 0x3FC0u) { ok = 0; break; }
        }
        *sflag = ok;
    }
    __syncthreads();
    return *sflag;
}

// ---------------------------------------------------------------------------
// proj: yT[n][l][r] = sum_c Wcat[r][c] * x[n][c][l]  (pixel-major bf16).
// Block 384 = 6 waves = 2 px-subs(32 px) x 3 row-groups(32 rows).
// Wave: 4 MFMA tiles (2 px x 2 row), K pipelined 2 deep. Grid 784 -> 4704
// waves (18.4/CU). Block 0 also builds the prep array.
// ---------------------------------------------------------------------------
struct Stage { unsigned int b[8]; bf16x8 a[2]; };

__device__ __forceinline__ void load_stage(
    int isb, const void* x, size_t xbase, int cb,
    const void* const (&wsA)[2], const int (&roA)[2], int col, Stage& st)
{
    if (isb) {
        const unsigned short* xb = (const unsigned short*)x;
        #pragma unroll
        for (int j = 0; j < 8; ++j)
            st.b[j] = *(const unsigned int*)(xb + xbase + (size_t)(cb + j) * HW);
        #pragma unroll
        for (int rt = 0; rt < 2; ++rt)
            st.a[rt] = *(const bf16x8*)((const unsigned short*)wsA[rt] + (roA[rt] + col) * 256 + cb);
    } else {
        const float* xb = (const float*)x;
        #pragma unroll
        for (int j = 0; j < 8; ++j) {
            float2 f = *(const float2*)(xb + xbase + (size_t)(cb + j) * HW);
            st.b[j] = (unsigned int)f2bf(f.x) | ((unsigned int)f2bf(f.y) << 16);
        }
        #pragma unroll
        for (int rt = 0; rt < 2; ++rt) {
            const float* fp = (const float*)wsA[rt] + (roA[rt] + col) * 256 + cb;
            bf16x8 af;
            #pragma unroll
            for (int j = 0; j < 8; ++j) af[j] = (short)f2bf(fp[j]);
            st.a[rt] = af;
        }
    }
}

__global__ __launch_bounds__(384) void proj_kernel(
    const void* __restrict__ x,
    const void* __restrict__ w1, const void* __restrict__ w2,
    const void* __restrict__ w3,
    const void* __restrict__ cpw, const void* __restrict__ cw1,
    const void* __restrict__ cw2,
    const void* __restrict__ b1g, const void* __restrict__ b1b,
    const void* __restrict__ b1m, const void* __restrict__ b1v,
    const void* __restrict__ b2g, const void* __restrict__ b2b,
    const void* __restrict__ b2m, const void* __restrict__ b2v,
    unsigned short* __restrict__ y,
    float* __restrict__ prep)
{
    __shared__ int sflag;
    const int isb = detect_bf16(b1v, &sflag);
    const int tid = threadIdx.x;

    if (blockIdx.x == 0) {
        for (int i = tid; i < 4;   i += 384) prep[P_CP + i] = ldp(cpw, i, isb);
        for (int i = tid; i < 288; i += 384) prep[P_W1 + i] = ldp(cw1, i, isb);
        for (int i = tid; i < 128; i += 384) prep[P_W2 + i] = ldp(cw2, i, isb);
        if (tid == 0) prep[P_FLAG] = isb ? 1.f : 0.f;
        for (int i = tid; i < HW; i += 384) {
            float a1 = ldp(b1g, i, isb) * rsqrtf(ldp(b1v, i, isb) + 1e-3f);
            float c1 = ldp(b1b, i, isb) - ldp(b1m, i, isb) * a1;
            float a2 = ldp(b2g, i, isb) * rsqrtf(ldp(b2v, i, isb) + 1e-3f);
            float c2 = ldp(b2b, i, isb) - ldp(b2m, i, isb) * a2;
            prep[P_BN + i]          = a1;
            prep[P_BN + HW + i]     = c1;
            prep[P_BN + 2 * HW + i] = a2;
            prep[P_BN + 3 * HW + i] = c2;
        }
    }

    const int blk  = blockIdx.x;
    const int n    = blk / 49;
    const int wave = tid >> 6, lane = tid & 63;
    const int s    = wave & 1;        // 32-px sub-group
    const int rg   = wave >> 1;       // 32-row group (0..2)
    const int col  = lane & 15, quad = lane >> 4;
    const int lb   = (blk - n * 49) * 64 + s * 32;
    const int px   = lb + 2 * col;

    const void* wsA[2]; int roA[2];
    if (rg == 0)      { wsA[0] = w1; roA[0] = 0;  wsA[1] = w2; roA[1] = 0;  }
    else if (rg == 1) { wsA[0] = w3; roA[0] = 0;  wsA[1] = w3; roA[1] = 16; }
    else              { wsA[0] = w3; roA[0] = 32; wsA[1] = w3; roA[1] = 48; }

    const size_t xbase = (size_t)n * 256 * HW + px;

    floatx4 acc[2][2];
    const floatx4 z4 = {0.f, 0.f, 0.f, 0.f};
    #pragma unroll
    for (int rt = 0; rt < 2; ++rt)
        #pragma unroll
        for (int t = 0; t < 2; ++t) acc[rt][t] = z4;

    Stage st[2];
    load_stage(isb, x, xbase, quad * 8, wsA, roA, col, st[0]);
    #pragma unroll
    for (int q = 0; q < 8; ++q) {
        if (q < 7)
            load_stage(isb, x, xbase, (q + 1) * 32 + quad * 8, wsA, roA, col, st[(q + 1) & 1]);
        Stage& c = st[q & 1];
        bf16x8 bt0, bt1;
        #pragma unroll
        for (int j = 0; j < 8; ++j) {
            bt0[j] = (short)(c.b[j] & 0xFFFFu);
            bt1[j] = (short)(c.b[j] >> 16);
        }
        #pragma unroll
        for (int rt = 0; rt < 2; ++rt) {
            acc[rt][0] = __builtin_amdgcn_mfma_f32_16x16x32_bf16(c.a[rt], bt0, acc[rt][0], 0, 0, 0);
            acc[rt][1] = __builtin_amdgcn_mfma_f32_16x16x32_bf16(c.a[rt], bt1, acc[rt][1], 0, 0, 0);
        }
    }

    // C/D: col -> pixel (2*col + t), row = rg*32 + rt*16 + quad*4 + g
    unsigned short* yb = y + ((size_t)n * HW + px) * 96 + rg * 32 + quad * 4;
    #pragma unroll
    for (int rt = 0; rt < 2; ++rt)
        #pragma unroll
        for (int t = 0; t < 2; ++t) {
            ushort4v pk;
            #pragma unroll
            for (int g = 0; g < 4; ++g) pk[g] = f2bf(acc[rt][t][g]);
            *(ushort4v*)(yb + (size_t)t * 96 + rt * 16) = pk;
        }
}

// ---------------------------------------------------------------------------
// Fused attention: block = 576 threads (9 waves) = 64 pixels.
// Phase 1: wave j, lane p -> pre-softmax h2[8] -> LDS.
// Phase 2: softmax over j in place. Phase 3: weighted neighbor aggregation.
// ---------------------------------------------------------------------------
__global__ __launch_bounds__(576) void attn_kernel(
    const unsigned short* __restrict__ yT,
    const float* __restrict__ prep,
    void* __restrict__ out)
{
    __shared__ float wsm[64 * WS];
    const int tid = threadIdx.x;
    const int blk = blockIdx.x;
    const int n   = blk / 49;
    const int l0  = (blk - n * 49) * 64;
    const int isb = prep[P_FLAG] != 0.f;

    // ---- phase 1: h2[8] per (pixel, j) ----
    {
        const int j = tid >> 6;            // 0..8, wave-uniform
        const int p = tid & 63;
        const int l = l0 + p;
        const int h = l / 56, w = l - h * 56;
        const int dy = j / 3 - 1, dx = j - (j / 3) * 3 - 1;
        int hh = h + dy; hh = (hh < 0) ? -hh : ((hh > 55) ? 110 - hh : hh);
        int ww = w + dx; ww = (ww < 0) ? -ww : ((ww > 55) ? 110 - ww : ww);
        const int nbr = hh * 56 + ww;

        const float a1 = prep[P_BN + l];
        const float c1 = prep[P_BN + HW + l];
        const float a2 = prep[P_BN + 2 * HW + l];
        const float c2 = prep[P_BN + 3 * HW + l];

        const unsigned short* y1p = yT + ((size_t)n * HW + l) * 96;
        const unsigned short* y2p = yT + ((size_t)n * HW + nbr) * 96 + 16;
        float y1f[16], y2f[16];
        unp8(*(const uint4*)y1p, y1f);       unp8(*(const uint4*)(y1p + 8), y1f + 8);
        unp8(*(const uint4*)y2p, y2f);       unp8(*(const uint4*)(y2p + 8), y2f + 8);

        float rel[18];
        #pragma unroll
        for (int c = 0; c < 16; ++c)
            rel[c] = fmaxf(fmaf(y1f[c] - y2f[c], a1, c1), 0.f);
        const float dlw = (float)(w - ww) * (2.0f / 55.0f);
        const float dlh = (float)(h - hh) * (2.0f / 55.0f);
        rel[16] = fmaxf(fmaf(prep[P_CP + 0] * dlw + prep[P_CP + 1] * dlh, a1, c1), 0.f);
        rel[17] = fmaxf(fmaf(prep[P_CP + 2] * dlw + prep[P_CP + 3] * dlh, a1, c1), 0.f);

        float h1[16];
        #pragma unroll
        for (int o = 0; o < 16; ++o) {
            float s = 0.f;
            #pragma unroll
            for (int c = 0; c < 18; ++c)
                s = fmaf(prep[P_W1 + o * 18 + c], rel[c], s);
            h1[o] = fmaxf(fmaf(s, a2, c2), 0.f);
        }
        float h2[8];
        #pragma unroll
        for (int o2 = 0; o2 < 8; ++o2) {
            float s = 0.f;
            #pragma unroll
            for (int o = 0; o < 16; ++o)
                s = fmaf(prep[P_W2 + o2 * 16 + o], h1[o], s);
            h2[o2] = s;
        }
        float* wp = &wsm[p * WS + j * 8];
        *(floatx4*)wp       = *(floatx4*)&h2[0];
        *(floatx4*)(wp + 4) = *(floatx4*)&h2[4];
    }
    __syncthreads();

    // ---- phase 2: softmax over j for each (p, c) ----
    if (tid < 512) {
        const int c = tid & 7, p = tid >> 3;
        float v[9];
        #pragma unroll
        for (int j = 0; j < 9; ++j) v[j] = wsm[p * WS + j * 8 + c];
        float m = v[0];
        #pragma unroll
        for (int j = 1; j < 9; ++j) m = fmaxf(m, v[j]);
        float s = 0.f;
        #pragma unroll
        for (int j = 0; j < 9; ++j) { v[j] = __expf(v[j] - m); s += v[j]; }
        const float inv = 1.f / s;
        #pragma unroll
        for (int j = 0; j < 9; ++j) wsm[p * WS + j * 8 + c] = v[j] * inv;
    }
    __syncthreads();

    // ---- phase 3: out[ch] = sum_j w[ch&7][j] * y3[ch][nbr_j] ----
    if (tid < 512) {
        const int p  = tid & 63;           // lane -> coalesced stores
        const int k8 = tid >> 6;           // channel group of 8
        const int l = l0 + p;
        const int h = l / 56, w = l - h * 56;
        int nbr[9];
        #pragma unroll
        for (int dy = 0; dy < 3; ++dy)
            #pragma unroll
            for (int dx = 0; dx < 3; ++dx) {
                int hh = h + dy - 1; hh = (hh < 0) ? -hh : ((hh > 55) ? 110 - hh : hh);
                int ww = w + dx - 1; ww = (ww < 0) ? -ww : ((ww > 55) ? 110 - ww : ww);
                nbr[dy * 3 + dx] = hh * 56 + ww;
            }
        const unsigned short* y3b = yT + (size_t)n * HW * 96 + 32 + k8 * 8;
        float acc8[8];
        #pragma unroll
        for (int k = 0; k < 8; ++k) acc8[k] = 0.f;
        #pragma unroll
        for (int j = 0; j < 9; ++j) {
            uint4 u = *(const uint4*)(y3b + (size_t)nbr[j] * 96);
            float yv[8];
            unp8(u, yv);
            const float* wp = &wsm[p * WS + j * 8];
            float2 w01 = *(const float2*)wp;
            float2 w23 = *(const float2*)(wp + 2);
            float2 w45 = *(const float2*)(wp + 4);
            float2 w67 = *(const float2*)(wp + 6);
            acc8[0] = fmaf(w01.x, yv[0], acc8[0]);
            acc8[1] = fmaf(w01.y, yv[1], acc8[1]);
            acc8[2] = fmaf(w23.x, yv[2], acc8[2]);
            acc8[3] = fmaf(w23.y, yv[3], acc8[3]);
            acc8[4] = fmaf(w45.x, yv[4], acc8[4]);
            acc8[5] = fmaf(w45.y, yv[5], acc8[5]);
            acc8[6] = fmaf(w67.x, yv[6], acc8[6]);
            acc8[7] = fmaf(w67.y, yv[7], acc8[7]);
        }
        const size_t obase = ((size_t)n * 64 + k8 * 8) * HW + l;
        #pragma unroll
        for (int k = 0; k < 8; ++k) {
            if (isb) ((unsigned short*)out)[obase + (size_t)k * HW] = f2bf(acc8[k]);
            else     ((float*)out)[obase + (size_t)k * HW]          = acc8[k];
        }
    }
}

extern "C" void kernel_launch(void* const* d_in, const int* in_sizes, int n_in,
                              void* d_out, int out_size, void* d_ws, size_t ws_size,
                              hipStream_t stream)
{
    const size_t yB = (size_t)NB * HW * 96 * 2;   // 9,633,792 B
    unsigned short* y = (unsigned short*)d_ws;
    float* prep = (float*)((char*)d_ws + yB);

    proj_kernel<<<dim3(784), dim3(384), 0, stream>>>(
        d_in[0], d_in[1], d_in[2], d_in[3],
        d_in[4], d_in[5], d_in[6],
        d_in[7], d_in[8], d_in[9], d_in[10],
        d_in[11], d_in[12], d_in[13], d_in[14],
        y, prep);

    attn_kernel<<<dim3(784), dim3(576), 0, stream>>>(y, prep, d_out);
}